// Round 3
// baseline (34789.572 us; speedup 1.0000x reference)
//
#include <hip/hip_runtime.h>
#include <hip/hip_bf16.h>

#define NS 4096
#define SEQ 2048
#define NBLK 256
#define SCAN_THREADS 512

typedef unsigned short ushort_t;

__device__ __forceinline__ float wred_sum(float v) {
#pragma unroll
  for (int o = 32; o > 0; o >>= 1) v += __shfl_xor(v, o, 64);
  return v;
}
__device__ __forceinline__ float wred_max(float v) {
#pragma unroll
  for (int o = 32; o > 0; o >>= 1) v = fmaxf(v, __shfl_xor(v, o, 64));
  return v;
}
__device__ __forceinline__ float bflo(unsigned u) { return __uint_as_float(u << 16); }
__device__ __forceinline__ float bfhi(unsigned u) { return __uint_as_float(u & 0xffff0000u); }

// ---- K1a: per-row softmax stats of T (rows r = i*2+sym, length 4096) ----
__global__ void rowstats_kernel(const float* __restrict__ T, float2* __restrict__ rstat) {
  const int r = blockIdx.x;
  const float* row = T + (size_t)r * NS;
  const int tid = threadIdx.x;
  float4 v[4];
  float mx = -1e30f;
#pragma unroll
  for (int q = 0; q < 4; ++q) {
    v[q] = *(const float4*)(row + q * 1024 + tid * 4);
    mx = fmaxf(mx, fmaxf(fmaxf(v[q].x, v[q].y), fmaxf(v[q].z, v[q].w)));
  }
  __shared__ float redm[4], reds[4];
  mx = wred_max(mx);
  if ((tid & 63) == 0) redm[tid >> 6] = mx;
  __syncthreads();
  mx = fmaxf(fmaxf(redm[0], redm[1]), fmaxf(redm[2], redm[3]));
  float se = 0.f;
#pragma unroll
  for (int q = 0; q < 4; ++q)
    se += __expf(v[q].x - mx) + __expf(v[q].y - mx) + __expf(v[q].z - mx) + __expf(v[q].w - mx);
  se = wred_sum(se);
  if ((tid & 63) == 0) reds[tid >> 6] = se;
  __syncthreads();
  if (tid == 0) {
    float tot = reds[0] + reds[1] + reds[2] + reds[3];
    rstat[r] = make_float2(mx, 1.0f / tot);
  }
}

// ---- K1b: normalize + quantize bf16 + transpose -> Tt[sym][j][i] ----
__global__ void transq_kernel(const float* __restrict__ T, const float2* __restrict__ rstat,
                              ushort_t* __restrict__ Tt) {
  const int j = blockIdx.x * 256 + threadIdx.x;
  const int i0 = blockIdx.y * 16;
  const int sym = blockIdx.z;
  ushort_t o16[16] __attribute__((aligned(16)));
#pragma unroll
  for (int ii = 0; ii < 16; ++ii) {
    const int r = (i0 + ii) * 2 + sym;
    const float2 st = rstat[r];
    const float val = T[(size_t)r * NS + j];
    const float w = __expf(val - st.x) * st.y;
    __hip_bfloat16 h = __float2bfloat16(w);
    o16[ii] = *reinterpret_cast<ushort_t*>(&h);
  }
  ushort_t* dst = Tt + ((size_t)sym * NS + j) * NS + i0;
  *(uint4*)dst = *(uint4*)(&o16[0]);
  *(uint4*)(dst + 8) = *(uint4*)(&o16[8]);
}

// ---- K2: normalize O (8192 rows of 4), keep fp32 ----
__global__ void onnorm_kernel(const float* __restrict__ O, float* __restrict__ On) {
  const int r = blockIdx.x * blockDim.x + threadIdx.x;
  if (r >= NS * 2) return;
  float4 v = *(const float4*)(O + (size_t)r * 4);
  float mx = fmaxf(fmaxf(v.x, v.y), fmaxf(v.z, v.w));
  float e0 = __expf(v.x - mx), e1 = __expf(v.y - mx), e2 = __expf(v.z - mx), e3 = __expf(v.w - mx);
  float inv = 1.0f / (e0 + e1 + e2 + e3);
  *(float4*)(On + (size_t)r * 4) = make_float4(e0 * inv, e1 * inv, e2 * inv, e3 * inv);
}

// ---- K2b: s0 = softmax(init) -> states[0] ----
__global__ void initstate_kernel(const float* __restrict__ init, float* __restrict__ s0) {
  const int tid = threadIdx.x;  // 1024 threads
  float4 v = *(const float4*)(init + tid * 4);
  float mx = fmaxf(fmaxf(v.x, v.y), fmaxf(v.z, v.w));
  __shared__ float red[16];
  mx = wred_max(mx);
  if ((tid & 63) == 0) red[tid >> 6] = mx;
  __syncthreads();
  float MX = -1e30f;
#pragma unroll
  for (int k = 0; k < 16; ++k) MX = fmaxf(MX, red[k]);
  __syncthreads();
  float e0 = __expf(v.x - MX), e1 = __expf(v.y - MX), e2 = __expf(v.z - MX), e3 = __expf(v.w - MX);
  float se = wred_sum(e0 + e1 + e2 + e3);
  if ((tid & 63) == 0) red[tid >> 6] = se;
  __syncthreads();
  float tot = 0.f;
#pragma unroll
  for (int k = 0; k < 16; ++k) tot += red[k];
  float inv = 1.0f / tot;
  *(float4*)(s0 + tid * 4) = make_float4(e0 * inv, e1 * inv, e2 * inv, e3 * inv);
}

// ---- K3: sequential scan, persistent cooperative kernel ----
// 256 blocks x 512 thr (8 waves); each wave owns 2 output columns.
// Register double-buffer (qa/qb) prefetches step t+1's T-columns before
// computing step t, hiding the L2/L3 fetch latency under the FMA phase.
struct ScanCtx {
  const ushort_t* Tt;
  float* states;
  unsigned* bar;
  int lane, wave, blk, jbase;
  unsigned nblk;
  float* smem;
  const int* sseq;
};

__device__ __forceinline__ void issue_cols(const ScanCtx& c, int sym, uint4 q[2][8]) {
  const ushort_t* colbase = c.Tt + ((size_t)sym * NS + c.jbase) * NS;
#pragma unroll
  for (int m = 0; m < 8; ++m) {
    q[0][m] = *(const uint4*)(colbase + m * 512 + c.lane * 8);
    q[1][m] = *(const uint4*)(colbase + NS + m * 512 + c.lane * 8);
  }
}

__device__ __forceinline__ void scan_step(const ScanCtx& c, int t,
                                          uint4 qcur[2][8], uint4 qnxt[2][8]) {
  const int tid = threadIdx.x;
  // wait for state_t to be published (t=0: ready at launch)
  if (t > 0) {
    if (tid == 0) {
      const unsigned target = (unsigned)t * c.nblk;
      while (__hip_atomic_load(c.bar, __ATOMIC_RELAXED, __HIP_MEMORY_SCOPE_AGENT) < target) {
        __builtin_amdgcn_s_sleep(1);
      }
    }
    __syncthreads();
  }
  // stage state_t -> LDS (512 thr x 8 floats)
  const float* s = c.states + (size_t)t * NS;
  {
    const int i0 = tid * 8;
    *(float4*)(c.smem + i0) = *(const float4*)(s + i0);
    *(float4*)(c.smem + i0 + 4) = *(const float4*)(s + i0 + 4);
  }
  __syncthreads();

  // prefetch next step's columns while we compute this step
  if (t + 1 < SEQ - 1) issue_cols(c, c.sseq[t + 1], qnxt);

  float a0 = 0.f, a1 = 0.f;
#pragma unroll
  for (int m = 0; m < 8; ++m) {
    const float4 s0 = *(const float4*)(c.smem + m * 512 + c.lane * 8);
    const float4 s1 = *(const float4*)(c.smem + m * 512 + c.lane * 8 + 4);
    const uint4 u = qcur[0][m];
    const uint4 v = qcur[1][m];
    a0 += s0.x * bflo(u.x) + s0.y * bfhi(u.x) + s0.z * bflo(u.y) + s0.w * bfhi(u.y);
    a0 += s1.x * bflo(u.z) + s1.y * bfhi(u.z) + s1.z * bflo(u.w) + s1.w * bfhi(u.w);
    a1 += s0.x * bflo(v.x) + s0.y * bfhi(v.x) + s0.z * bflo(v.y) + s0.w * bfhi(v.y);
    a1 += s1.x * bflo(v.z) + s1.y * bfhi(v.z) + s1.z * bflo(v.w) + s1.w * bfhi(v.w);
  }
  a0 = wred_sum(a0);
  a1 = wred_sum(a1);
  if (c.lane == 0) {
    *(float2*)(c.states + (size_t)(t + 1) * NS + c.jbase) = make_float2(a0, a1);
  }
  __syncthreads();  // all waves' stores drained before arrival
  if (tid == 0) {
    __hip_atomic_fetch_add(c.bar, 1u, __ATOMIC_RELEASE, __HIP_MEMORY_SCOPE_AGENT);
  }
}

__global__ void __launch_bounds__(SCAN_THREADS, 2)
scan_kernel(const ushort_t* __restrict__ Tt, const int* __restrict__ seq,
            float* __restrict__ states, unsigned* __restrict__ bar) {
  __shared__ float smem[NS];
  __shared__ int sseq[SEQ];
  const int tid = threadIdx.x;

  ScanCtx c;
  c.Tt = Tt;
  c.states = states;
  c.bar = bar;
  c.lane = tid & 63;
  c.wave = tid >> 6;
  c.blk = blockIdx.x;
  c.jbase = c.blk * 16 + c.wave * 2;
  c.nblk = gridDim.x;
  c.smem = smem;
  c.sseq = sseq;

  for (int k = tid; k < SEQ; k += SCAN_THREADS) sseq[k] = seq[k];
  __syncthreads();

  uint4 qa[2][8], qb[2][8];
  issue_cols(c, sseq[0], qa);

  for (int t = 0; t < SEQ - 1; t += 2) {
    scan_step(c, t, qa, qb);
    if (t + 1 < SEQ - 1) scan_step(c, t + 1, qb, qa);
  }
}

// ---- K4: out[t,:] = (s_t @ On[:,y,:]) / sum(s_t)  (mass-normalized) ----
__global__ void output_kernel(const float* __restrict__ states, const float* __restrict__ On,
                              const int* __restrict__ seq, float* __restrict__ out) {
  const int t = blockIdx.x;
  const int y = seq[t];
  const float* s = states + (size_t)t * NS;
  const int tid = threadIdx.x;
  float a0 = 0, a1 = 0, a2 = 0, a3 = 0, mass = 0;
  for (int q = 0; q < 16; ++q) {
    const int i = q * 256 + tid;
    const float sv = s[i];
    const float4 on = *(const float4*)(On + ((size_t)i * 2 + y) * 4);
    a0 += sv * on.x; a1 += sv * on.y; a2 += sv * on.z; a3 += sv * on.w; mass += sv;
  }
  a0 = wred_sum(a0); a1 = wred_sum(a1); a2 = wred_sum(a2); a3 = wred_sum(a3);
  mass = wred_sum(mass);
  __shared__ float red[4][5];
  const int lane = tid & 63, wave = tid >> 6;
  if (lane == 0) { red[wave][0] = a0; red[wave][1] = a1; red[wave][2] = a2;
                   red[wave][3] = a3; red[wave][4] = mass; }
  __syncthreads();
  if (tid == 0) {
    float b0 = red[0][0] + red[1][0] + red[2][0] + red[3][0];
    float b1 = red[0][1] + red[1][1] + red[2][1] + red[3][1];
    float b2 = red[0][2] + red[1][2] + red[2][2] + red[3][2];
    float b3 = red[0][3] + red[1][3] + red[2][3] + red[3][3];
    float M  = red[0][4] + red[1][4] + red[2][4] + red[3][4];
    const float inv = 1.0f / M;
    *(float4*)(out + (size_t)t * 4) = make_float4(b0 * inv, b1 * inv, b2 * inv, b3 * inv);
  }
}

extern "C" void kernel_launch(void* const* d_in, const int* in_sizes, int n_in,
                              void* d_out, int out_size, void* d_ws, size_t ws_size,
                              hipStream_t stream) {
  const int* seq    = (const int*)d_in[0];
  const float* T    = (const float*)d_in[1];
  const float* O    = (const float*)d_in[2];
  const float* init = (const float*)d_in[3];
  float* out = (float*)d_out;

  char* ws = (char*)d_ws;
  // layout: Tt bf16 [2][4096][4096] | states f32 [2048][4096] | On f32 | rstat | bar
  ushort_t* Tt  = (ushort_t*)ws;                                   // 64 MiB
  float* states = (float*)(ws + 67108864);                         // 32 MiB
  float* On     = (float*)(ws + 67108864 + 33554432);              // 128 KiB
  float2* rstat = (float2*)(ws + 67108864 + 33554432 + 131072);    // 64 KiB
  unsigned* bar = (unsigned*)(ws + 67108864 + 33554432 + 131072 + 65536);

  (void)hipMemsetAsync(bar, 0, 64, stream);
  hipLaunchKernelGGL(rowstats_kernel, dim3(NS * 2), dim3(256), 0, stream, T, rstat);
  hipLaunchKernelGGL(transq_kernel, dim3(16, 256, 2), dim3(256), 0, stream, T, rstat, Tt);
  hipLaunchKernelGGL(onnorm_kernel, dim3(32), dim3(256), 0, stream, O, On);
  hipLaunchKernelGGL(initstate_kernel, dim3(1), dim3(1024), 0, stream, init, states);

  void* kargs[] = { (void*)&Tt, (void*)&seq, (void*)&states, (void*)&bar };
  (void)hipLaunchCooperativeKernel((void*)scan_kernel, dim3(NBLK), dim3(SCAN_THREADS),
                                   kargs, 0, stream);

  hipLaunchKernelGGL(output_kernel, dim3(SEQ), dim3(256), 0, stream, states, On, seq, out);
}

// Round 5
// 16375.050 us; speedup vs baseline: 2.1245x; 2.1245x over previous
//
#include <hip/hip_runtime.h>
#include <hip/hip_bf16.h>

#define NS 4096
#define SEQ 2048
#define NBLK 256
#define THR 1024
#define NCTR 16  // barrier counters, 64B apart

typedef unsigned short ushort_t;
typedef float vfloat2 __attribute__((ext_vector_type(2)));

__device__ __forceinline__ float wred_sum(float v) {
#pragma unroll
  for (int o = 32; o > 0; o >>= 1) v += __shfl_xor(v, o, 64);
  return v;
}
__device__ __forceinline__ float wred_max(float v) {
#pragma unroll
  for (int o = 32; o > 0; o >>= 1) v = fmaxf(v, __shfl_xor(v, o, 64));
  return v;
}

// fp8 e4m3fn (OCP), all values positive, no subnormals by construction.
#if __has_builtin(__builtin_amdgcn_cvt_pk_f32_fp8)
template <bool W>
__device__ __forceinline__ vfloat2 cvtpk(unsigned d) {
  return __builtin_amdgcn_cvt_pk_f32_fp8((int)d, W);
}
#else
template <bool W>
__device__ __forceinline__ vfloat2 cvtpk(unsigned d) {
  unsigned b0 = (d >> (W ? 16 : 0)) & 0x7fu;
  unsigned b1 = (d >> (W ? 24 : 8)) & 0x7fu;
  vfloat2 r;
  r.x = __uint_as_float((b0 << 20) + 0x3C000000u);
  r.y = __uint_as_float((b1 << 20) + 0x3C000000u);
  return r;
}
#endif

__device__ __forceinline__ float dot4_fp8(unsigned d, float4 s, float acc) {
  vfloat2 lo = cvtpk<false>(d);
  vfloat2 hi = cvtpk<true>(d);
  acc += s.x * lo.x; acc += s.y * lo.y;
  acc += s.z * hi.x; acc += s.w * hi.y;
  return acc;
}

// ---- K1a: per-row softmax stats of T. inv includes x4096 scale so the
// normalized weights land ~1.0 (fp8 e4m3 sweet spot). Global scale cancels
// via the mass-normalized epilogue + 1/4096 per step.
__global__ void rowstats_kernel(const float* __restrict__ T, float2* __restrict__ rstat) {
  const int r = blockIdx.x;
  const float* row = T + (size_t)r * NS;
  const int tid = threadIdx.x;
  float4 v[4];
  float mx = -1e30f;
#pragma unroll
  for (int q = 0; q < 4; ++q) {
    v[q] = *(const float4*)(row + q * 1024 + tid * 4);
    mx = fmaxf(mx, fmaxf(fmaxf(v[q].x, v[q].y), fmaxf(v[q].z, v[q].w)));
  }
  __shared__ float redm[4], reds[4];
  mx = wred_max(mx);
  if ((tid & 63) == 0) redm[tid >> 6] = mx;
  __syncthreads();
  mx = fmaxf(fmaxf(redm[0], redm[1]), fmaxf(redm[2], redm[3]));
  float se = 0.f;
#pragma unroll
  for (int q = 0; q < 4; ++q)
    se += __expf(v[q].x - mx) + __expf(v[q].y - mx) + __expf(v[q].z - mx) + __expf(v[q].w - mx);
  se = wred_sum(se);
  if ((tid & 63) == 0) reds[tid >> 6] = se;
  __syncthreads();
  if (tid == 0) {
    float tot = reds[0] + reds[1] + reds[2] + reds[3];
    rstat[r] = make_float2(mx, 4096.0f / tot);
  }
}

// ---- K1b: normalize (x4096) + bf16 + transpose -> Tt16[sym][j][i] ----
__global__ void transq_kernel(const float* __restrict__ T, const float2* __restrict__ rstat,
                              ushort_t* __restrict__ Tt16) {
  const int j = blockIdx.x * 256 + threadIdx.x;
  const int i0 = blockIdx.y * 16;
  const int sym = blockIdx.z;
  ushort_t o16[16] __attribute__((aligned(16)));
#pragma unroll
  for (int ii = 0; ii < 16; ++ii) {
    const int r = (i0 + ii) * 2 + sym;
    const float2 st = rstat[r];
    const float val = T[(size_t)r * NS + j];
    const float w = __expf(val - st.x) * st.y;  // ~1.0 scale
    __hip_bfloat16 h = __float2bfloat16(w);
    o16[ii] = *reinterpret_cast<ushort_t*>(&h);
  }
  ushort_t* dst = Tt16 + ((size_t)sym * NS + j) * NS + i0;
  *(uint4*)dst = *(uint4*)(&o16[0]);
  *(uint4*)(dst + 8) = *(uint4*)(&o16[8]);
}

// ---- K1c: quantize fp8 + permute within column for conflict-free LDS reads.
// dst byte o = q*1024 + l*16 + r*4 + e  holds weight for state index
// i = q*1024 + r*256 + l*4 + e  (q=0..3 load, l=lane, r=dword, e=byte).
__device__ __forceinline__ unsigned char enc8(unsigned bf) {
  // bf16 bits -> e4m3fn with round-half-up; value in [~0.3, ~3.5], positive.
  return (unsigned char)((((bf << 16) + 0xC4080000u) >> 20) & 0x7Fu);
}
__global__ void permq_kernel(const ushort_t* __restrict__ Tt16, unsigned char* __restrict__ Tt8) {
  const int t = threadIdx.x;       // 256
  const int colid = blockIdx.x;    // sym*4096 + j
  const ushort_t* src = Tt16 + (size_t)colid * NS;
  const int q = t >> 6, l = t & 63;
  unsigned char ob[16] __attribute__((aligned(16)));
#pragma unroll
  for (int r = 0; r < 4; ++r) {
    const int i0 = q * 1024 + r * 256 + l * 4;
    uint2 u2 = *(const uint2*)(src + i0);
    ob[r * 4 + 0] = enc8(u2.x & 0xffffu);
    ob[r * 4 + 1] = enc8(u2.x >> 16);
    ob[r * 4 + 2] = enc8(u2.y & 0xffffu);
    ob[r * 4 + 3] = enc8(u2.y >> 16);
  }
  *(uint4*)(Tt8 + (size_t)colid * NS + t * 16) = *(uint4*)ob;
}

// ---- K2: normalize O, keep fp32 ----
__global__ void onnorm_kernel(const float* __restrict__ O, float* __restrict__ On) {
  const int r = blockIdx.x * blockDim.x + threadIdx.x;
  if (r >= NS * 2) return;
  float4 v = *(const float4*)(O + (size_t)r * 4);
  float mx = fmaxf(fmaxf(v.x, v.y), fmaxf(v.z, v.w));
  float e0 = __expf(v.x - mx), e1 = __expf(v.y - mx), e2 = __expf(v.z - mx), e3 = __expf(v.w - mx);
  float inv = 1.0f / (e0 + e1 + e2 + e3);
  *(float4*)(On + (size_t)r * 4) = make_float4(e0 * inv, e1 * inv, e2 * inv, e3 * inv);
}

// ---- K2b: s0 = softmax(init) * 4096 -> states[0] ----
__global__ void initstate_kernel(const float* __restrict__ init, float* __restrict__ s0) {
  const int tid = threadIdx.x;  // 1024
  float4 v = *(const float4*)(init + tid * 4);
  float mx = fmaxf(fmaxf(v.x, v.y), fmaxf(v.z, v.w));
  __shared__ float red[16];
  mx = wred_max(mx);
  if ((tid & 63) == 0) red[tid >> 6] = mx;
  __syncthreads();
  float MX = -1e30f;
#pragma unroll
  for (int k = 0; k < 16; ++k) MX = fmaxf(MX, red[k]);
  __syncthreads();
  float e0 = __expf(v.x - MX), e1 = __expf(v.y - MX), e2 = __expf(v.z - MX), e3 = __expf(v.w - MX);
  float se = wred_sum(e0 + e1 + e2 + e3);
  if ((tid & 63) == 0) red[tid >> 6] = se;
  __syncthreads();
  float tot = 0.f;
#pragma unroll
  for (int k = 0; k < 16; ++k) tot += red[k];
  float inv = 4096.0f / tot;
  *(float4*)(s0 + tid * 4) = make_float4(e0 * inv, e1 * inv, e2 * inv, e3 * inv);
}

// ---- K3: sequential scan. 256 blocks x 1024 thr (16 waves = 1 col each).
// Register double-buffer: 4 uint4/lane per buffer (fp8) -> fits in 128 VGPR,
// no spill. Split barrier: 16 counters, 16 blocks each, parallel arrivals.
__global__ void __launch_bounds__(THR, 4)
scan_kernel(const unsigned char* __restrict__ Tt8, const int* __restrict__ seq,
            float* __restrict__ states, unsigned* __restrict__ bar) {
  __shared__ float smem[NS];
  __shared__ int sseq[SEQ];
  const int tid = threadIdx.x;
  const int lane = tid & 63;
  const int wave = tid >> 6;
  const int blk = blockIdx.x;
  const int col = blk * 16 + wave;

  for (int k = tid; k < SEQ; k += THR) sseq[k] = seq[k];
  __syncthreads();

  uint4 qa0, qa1, qa2, qa3, qb0, qb1, qb2, qb3;
  {
    const unsigned char* cb = Tt8 + ((size_t)sseq[0] * NS + col) * NS + lane * 16;
    qa0 = *(const uint4*)(cb);
    qa1 = *(const uint4*)(cb + 1024);
    qa2 = *(const uint4*)(cb + 2048);
    qa3 = *(const uint4*)(cb + 3072);
  }

  for (int t = 0; t < SEQ - 1; ++t) {
    // (a) wait for state t (t=0 ready via kernel ordering)
    if (t > 0) {
      if (wave == 0) {
        const unsigned tgt = (unsigned)(NBLK / NCTR) * (unsigned)t;
        const unsigned* myc = bar + (lane & (NCTR - 1)) * 16;
        unsigned cv;
        do {
          cv = __hip_atomic_load(myc, __ATOMIC_RELAXED, __HIP_MEMORY_SCOPE_AGENT);
        } while (!__all(cv >= tgt));
      }
      __syncthreads();  // orders spin-exit before state reads, all waves
    }

    // (b) issue prefetch of next symbol's column (independent of state)
    const int tn = t + 1;
    if (tn < SEQ - 1) {
      const unsigned char* cb = Tt8 + ((size_t)sseq[tn] * NS + col) * NS + lane * 16;
      qb0 = *(const uint4*)(cb);
      qb1 = *(const uint4*)(cb + 1024);
      qb2 = *(const uint4*)(cb + 2048);
      qb3 = *(const uint4*)(cb + 3072);
    }

    // (c) stage state t -> LDS (1024 thr x 16B, conflict-free)
    const float* s = states + (size_t)t * NS;
    *(float4*)(smem + tid * 4) = *(const float4*)(s + tid * 4);
    __syncthreads();

    // (d) compute: per q, 4 ds_read_b128 (consecutive lanes -> consecutive
    // float4 -> zero bank conflicts) + 16 fp8 decode-FMAs
    float a = 0.f;
#define DOQ(Q, qi)                                                     \
    {                                                                  \
      float4 s0 = *(const float4*)(smem + qi * 1024 + lane * 4);       \
      float4 s1 = *(const float4*)(smem + qi * 1024 + 256 + lane * 4); \
      float4 s2 = *(const float4*)(smem + qi * 1024 + 512 + lane * 4); \
      float4 s3 = *(const float4*)(smem + qi * 1024 + 768 + lane * 4); \
      a = dot4_fp8(Q.x, s0, a);                                        \
      a = dot4_fp8(Q.y, s1, a);                                        \
      a = dot4_fp8(Q.z, s2, a);                                        \
      a = dot4_fp8(Q.w, s3, a);                                        \
    }
    DOQ(qa0, 0) DOQ(qa1, 1) DOQ(qa2, 2) DOQ(qa3, 3)
#undef DOQ

    a = wred_sum(a);
    if (lane == 0) states[(size_t)(t + 1) * NS + col] = a * (1.0f / 4096.0f);
    __syncthreads();  // each wave drains its store before barrier
    if (tid == 0) {
      __hip_atomic_fetch_add(bar + (blk & (NCTR - 1)) * 16, 1u,
                             __ATOMIC_RELEASE, __HIP_MEMORY_SCOPE_AGENT);
    }
    qa0 = qb0; qa1 = qb1; qa2 = qb2; qa3 = qb3;
  }
}

// ---- K4: out[t,:] = (s_t @ On[:,y,:]) / sum(s_t) (mass-normalized; cancels
// fp8 drift and the x4096 scale) ----
__global__ void output_kernel(const float* __restrict__ states, const float* __restrict__ On,
                              const int* __restrict__ seq, float* __restrict__ out) {
  const int t = blockIdx.x;
  const int y = seq[t];
  const float* s = states + (size_t)t * NS;
  const int tid = threadIdx.x;
  float a0 = 0, a1 = 0, a2 = 0, a3 = 0, mass = 0;
  for (int q = 0; q < 16; ++q) {
    const int i = q * 256 + tid;
    const float sv = s[i];
    const float4 on = *(const float4*)(On + ((size_t)i * 2 + y) * 4);
    a0 += sv * on.x; a1 += sv * on.y; a2 += sv * on.z; a3 += sv * on.w; mass += sv;
  }
  a0 = wred_sum(a0); a1 = wred_sum(a1); a2 = wred_sum(a2); a3 = wred_sum(a3);
  mass = wred_sum(mass);
  __shared__ float red[4][5];
  const int lane = tid & 63, wave = tid >> 6;
  if (lane == 0) { red[wave][0] = a0; red[wave][1] = a1; red[wave][2] = a2;
                   red[wave][3] = a3; red[wave][4] = mass; }
  __syncthreads();
  if (tid == 0) {
    float b0 = red[0][0] + red[1][0] + red[2][0] + red[3][0];
    float b1 = red[0][1] + red[1][1] + red[2][1] + red[3][1];
    float b2 = red[0][2] + red[1][2] + red[2][2] + red[3][2];
    float b3 = red[0][3] + red[1][3] + red[2][3] + red[3][3];
    float M  = red[0][4] + red[1][4] + red[2][4] + red[3][4];
    const float inv = 1.0f / M;
    *(float4*)(out + (size_t)t * 4) = make_float4(b0 * inv, b1 * inv, b2 * inv, b3 * inv);
  }
}

extern "C" void kernel_launch(void* const* d_in, const int* in_sizes, int n_in,
                              void* d_out, int out_size, void* d_ws, size_t ws_size,
                              hipStream_t stream) {
  const int* seq    = (const int*)d_in[0];
  const float* T    = (const float*)d_in[1];
  const float* O    = (const float*)d_in[2];
  const float* init = (const float*)d_in[3];
  float* out = (float*)d_out;

  char* ws = (char*)d_ws;
  // layout: Tt8 [32MiB] | A [64MiB: Tt16 during preproc, then states 32MiB] |
  //         On | rstat | bar   (states overlaps Tt16 -> total ~97 MiB)
  unsigned char* Tt8 = (unsigned char*)ws;                    // 32 MiB
  ushort_t* Tt16 = (ushort_t*)(ws + 33554432);                // 64 MiB (temp)
  float* states  = (float*)(ws + 33554432);                   // 32 MiB (reuse)
  float* On      = (float*)(ws + 33554432 + 67108864);
  float2* rstat  = (float2*)(ws + 33554432 + 67108864 + 131072);
  unsigned* bar  = (unsigned*)(ws + 33554432 + 67108864 + 131072 + 65536);

  (void)hipMemsetAsync(bar, 0, NCTR * 64, stream);
  hipLaunchKernelGGL(rowstats_kernel, dim3(NS * 2), dim3(256), 0, stream, T, rstat);
  hipLaunchKernelGGL(transq_kernel, dim3(16, 256, 2), dim3(256), 0, stream, T, rstat, Tt16);
  hipLaunchKernelGGL(permq_kernel, dim3(NS * 2), dim3(256), 0, stream, Tt16, Tt8);
  hipLaunchKernelGGL(onnorm_kernel, dim3(32), dim3(256), 0, stream, O, On);
  // initstate AFTER permq: states region overlaps Tt16 (stream-ordered)
  hipLaunchKernelGGL(initstate_kernel, dim3(1), dim3(1024), 0, stream, init, states);

  void* kargs[] = { (void*)&Tt8, (void*)&seq, (void*)&states, (void*)&bar };
  (void)hipLaunchCooperativeKernel((void*)scan_kernel, dim3(NBLK), dim3(THR),
                                   kargs, 0, stream);

  hipLaunchKernelGGL(output_kernel, dim3(SEQ), dim3(256), 0, stream, states, On, seq, out);
}

// Round 6
// 13951.102 us; speedup vs baseline: 2.4937x; 1.1737x over previous
//
#include <hip/hip_runtime.h>
#include <hip/hip_bf16.h>

#define NS 4096
#define SEQ 2048
#define NBLK 256
#define THR 1024

typedef unsigned short ushort_t;
typedef float vfloat2 __attribute__((ext_vector_type(2)));

__device__ __forceinline__ float wred_sum(float v) {
#pragma unroll
  for (int o = 32; o > 0; o >>= 1) v += __shfl_xor(v, o, 64);
  return v;
}
__device__ __forceinline__ float wred_max(float v) {
#pragma unroll
  for (int o = 32; o > 0; o >>= 1) v = fmaxf(v, __shfl_xor(v, o, 64));
  return v;
}

// fp8 e4m3fn (OCP), all values positive, no subnormals by construction.
#if __has_builtin(__builtin_amdgcn_cvt_pk_f32_fp8)
template <bool W>
__device__ __forceinline__ vfloat2 cvtpk(unsigned d) {
  return __builtin_amdgcn_cvt_pk_f32_fp8((int)d, W);
}
#else
template <bool W>
__device__ __forceinline__ vfloat2 cvtpk(unsigned d) {
  unsigned b0 = (d >> (W ? 16 : 0)) & 0x7fu;
  unsigned b1 = (d >> (W ? 24 : 8)) & 0x7fu;
  vfloat2 r;
  r.x = __uint_as_float((b0 << 20) + 0x3C000000u);
  r.y = __uint_as_float((b1 << 20) + 0x3C000000u);
  return r;
}
#endif

__device__ __forceinline__ float dot4_fp8(unsigned d, float4 s, float acc) {
  vfloat2 lo = cvtpk<false>(d);
  vfloat2 hi = cvtpk<true>(d);
  acc += s.x * lo.x; acc += s.y * lo.y;
  acc += s.z * hi.x; acc += s.w * hi.y;
  return acc;
}

// ---- K1a: per-row softmax stats of T (x4096 scale folded into inv) ----
__global__ void rowstats_kernel(const float* __restrict__ T, float2* __restrict__ rstat) {
  const int r = blockIdx.x;
  const float* row = T + (size_t)r * NS;
  const int tid = threadIdx.x;
  float4 v[4];
  float mx = -1e30f;
#pragma unroll
  for (int q = 0; q < 4; ++q) {
    v[q] = *(const float4*)(row + q * 1024 + tid * 4);
    mx = fmaxf(mx, fmaxf(fmaxf(v[q].x, v[q].y), fmaxf(v[q].z, v[q].w)));
  }
  __shared__ float redm[4], reds[4];
  mx = wred_max(mx);
  if ((tid & 63) == 0) redm[tid >> 6] = mx;
  __syncthreads();
  mx = fmaxf(fmaxf(redm[0], redm[1]), fmaxf(redm[2], redm[3]));
  float se = 0.f;
#pragma unroll
  for (int q = 0; q < 4; ++q)
    se += __expf(v[q].x - mx) + __expf(v[q].y - mx) + __expf(v[q].z - mx) + __expf(v[q].w - mx);
  se = wred_sum(se);
  if ((tid & 63) == 0) reds[tid >> 6] = se;
  __syncthreads();
  if (tid == 0) {
    float tot = reds[0] + reds[1] + reds[2] + reds[3];
    rstat[r] = make_float2(mx, 4096.0f / tot);
  }
}

// ---- K1b: normalize (x4096) + bf16 + transpose -> Tt16[sym][j][i] ----
__global__ void transq_kernel(const float* __restrict__ T, const float2* __restrict__ rstat,
                              ushort_t* __restrict__ Tt16) {
  const int j = blockIdx.x * 256 + threadIdx.x;
  const int i0 = blockIdx.y * 16;
  const int sym = blockIdx.z;
  ushort_t o16[16] __attribute__((aligned(16)));
#pragma unroll
  for (int ii = 0; ii < 16; ++ii) {
    const int r = (i0 + ii) * 2 + sym;
    const float2 st = rstat[r];
    const float val = T[(size_t)r * NS + j];
    const float w = __expf(val - st.x) * st.y;  // ~1.0 scale
    __hip_bfloat16 h = __float2bfloat16(w);
    o16[ii] = *reinterpret_cast<ushort_t*>(&h);
  }
  ushort_t* dst = Tt16 + ((size_t)sym * NS + j) * NS + i0;
  *(uint4*)dst = *(uint4*)(&o16[0]);
  *(uint4*)(dst + 8) = *(uint4*)(&o16[8]);
}

// ---- K1c: quantize fp8 + permute within column for conflict-free LDS reads.
__device__ __forceinline__ unsigned char enc8(unsigned bf) {
  return (unsigned char)((((bf << 16) + 0xC4080000u) >> 20) & 0x7Fu);
}
__global__ void permq_kernel(const ushort_t* __restrict__ Tt16, unsigned char* __restrict__ Tt8) {
  const int t = threadIdx.x;       // 256
  const int colid = blockIdx.x;    // sym*4096 + j
  const ushort_t* src = Tt16 + (size_t)colid * NS;
  const int q = t >> 6, l = t & 63;
  unsigned char ob[16] __attribute__((aligned(16)));
#pragma unroll
  for (int r = 0; r < 4; ++r) {
    const int i0 = q * 1024 + r * 256 + l * 4;
    uint2 u2 = *(const uint2*)(src + i0);
    ob[r * 4 + 0] = enc8(u2.x & 0xffffu);
    ob[r * 4 + 1] = enc8(u2.x >> 16);
    ob[r * 4 + 2] = enc8(u2.y & 0xffffu);
    ob[r * 4 + 3] = enc8(u2.y >> 16);
  }
  *(uint4*)(Tt8 + (size_t)colid * NS + t * 16) = *(uint4*)ob;
}

// ---- K2: normalize O, keep fp32 ----
__global__ void onnorm_kernel(const float* __restrict__ O, float* __restrict__ On) {
  const int r = blockIdx.x * blockDim.x + threadIdx.x;
  if (r >= NS * 2) return;
  float4 v = *(const float4*)(O + (size_t)r * 4);
  float mx = fmaxf(fmaxf(v.x, v.y), fmaxf(v.z, v.w));
  float e0 = __expf(v.x - mx), e1 = __expf(v.y - mx), e2 = __expf(v.z - mx), e3 = __expf(v.w - mx);
  float inv = 1.0f / (e0 + e1 + e2 + e3);
  *(float4*)(On + (size_t)r * 4) = make_float4(e0 * inv, e1 * inv, e2 * inv, e3 * inv);
}

// ---- K2b: s0 = softmax(init) * 4096 -> states[0] ----
__global__ void initstate_kernel(const float* __restrict__ init, float* __restrict__ s0) {
  const int tid = threadIdx.x;  // 1024
  float4 v = *(const float4*)(init + tid * 4);
  float mx = fmaxf(fmaxf(v.x, v.y), fmaxf(v.z, v.w));
  __shared__ float red[16];
  mx = wred_max(mx);
  if ((tid & 63) == 0) red[tid >> 6] = mx;
  __syncthreads();
  float MX = -1e30f;
#pragma unroll
  for (int k = 0; k < 16; ++k) MX = fmaxf(MX, red[k]);
  __syncthreads();
  float e0 = __expf(v.x - MX), e1 = __expf(v.y - MX), e2 = __expf(v.z - MX), e3 = __expf(v.w - MX);
  float se = wred_sum(e0 + e1 + e2 + e3);
  if ((tid & 63) == 0) red[tid >> 6] = se;
  __syncthreads();
  float tot = 0.f;
#pragma unroll
  for (int k = 0; k < 16; ++k) tot += red[k];
  float inv = 4096.0f / tot;
  *(float4*)(s0 + tid * 4) = make_float4(e0 * inv, e1 * inv, e2 * inv, e3 * inv);
}

// ---- K3: sequential scan. 256 blocks x 1024 thr (16 waves = 1 col each).
// Sync: per-block epoch flags (no shared-counter RMW serialization).
//  - state results: relaxed AGENT atomic stores (write-through to fabric)
//  - signal: flags[blk] = t+1, store-RELEASE (orders all block stores first)
//  - wait: wave0 polls all 256 flags (4 relaxed loads/lane), then barrier.
// Reader needs no acquire: states[t] lines are never previously touched by
// the reader's caches (monotone fresh addresses), so loads miss to fabric.
__global__ void __launch_bounds__(THR, 4)
scan_kernel(const unsigned char* __restrict__ Tt8, const int* __restrict__ seq,
            float* __restrict__ states, unsigned* __restrict__ flags) {
  __shared__ float smem[NS];
  __shared__ int sseq[SEQ];
  const int tid = threadIdx.x;
  const int lane = tid & 63;
  const int wave = tid >> 6;
  const int blk = blockIdx.x;
  const int col = blk * 16 + wave;

  for (int k = tid; k < SEQ; k += THR) sseq[k] = seq[k];
  __syncthreads();

  const unsigned* fp = flags + lane * 4;  // each lane watches 4 blocks

  uint4 qa0, qa1, qa2, qa3, qb0, qb1, qb2, qb3;
  {
    const unsigned char* cb = Tt8 + ((size_t)sseq[0] * NS + col) * NS + lane * 16;
    qa0 = *(const uint4*)(cb);
    qa1 = *(const uint4*)(cb + 1024);
    qa2 = *(const uint4*)(cb + 2048);
    qa3 = *(const uint4*)(cb + 3072);
  }

  for (int t = 0; t < SEQ - 1; ++t) {
    // (a) issue prefetch of next symbol's columns FIRST (overlaps the wait)
    const int tn = t + 1;
    if (tn < SEQ - 1) {
      const unsigned char* cb = Tt8 + ((size_t)sseq[tn] * NS + col) * NS + lane * 16;
      qb0 = *(const uint4*)(cb);
      qb1 = *(const uint4*)(cb + 1024);
      qb2 = *(const uint4*)(cb + 2048);
      qb3 = *(const uint4*)(cb + 3072);
    }

    // (b) wait for epoch t (t=0 ready via kernel ordering)
    if (t > 0) {
      if (wave == 0) {
        const unsigned tgt = (unsigned)t;
        unsigned f0, f1, f2, f3;
        do {
          f0 = __hip_atomic_load(fp + 0, __ATOMIC_RELAXED, __HIP_MEMORY_SCOPE_AGENT);
          f1 = __hip_atomic_load(fp + 1, __ATOMIC_RELAXED, __HIP_MEMORY_SCOPE_AGENT);
          f2 = __hip_atomic_load(fp + 2, __ATOMIC_RELAXED, __HIP_MEMORY_SCOPE_AGENT);
          f3 = __hip_atomic_load(fp + 3, __ATOMIC_RELAXED, __HIP_MEMORY_SCOPE_AGENT);
        } while (!__all(f0 >= tgt && f1 >= tgt && f2 >= tgt && f3 >= tgt));
      }
      __syncthreads();
    }

    // (c) stage state t -> LDS (1024 thr x 16B)
    const float* s = states + (size_t)t * NS;
    *(float4*)(smem + tid * 4) = *(const float4*)(s + tid * 4);
    __syncthreads();

    // (d) compute
    float a = 0.f;
#define DOQ(Q, qi)                                                     \
    {                                                                  \
      float4 s0 = *(const float4*)(smem + qi * 1024 + lane * 4);       \
      float4 s1 = *(const float4*)(smem + qi * 1024 + 256 + lane * 4); \
      float4 s2 = *(const float4*)(smem + qi * 1024 + 512 + lane * 4); \
      float4 s3 = *(const float4*)(smem + qi * 1024 + 768 + lane * 4); \
      a = dot4_fp8(Q.x, s0, a);                                        \
      a = dot4_fp8(Q.y, s1, a);                                        \
      a = dot4_fp8(Q.z, s2, a);                                        \
      a = dot4_fp8(Q.w, s3, a);                                        \
    }
    DOQ(qa0, 0) DOQ(qa1, 1) DOQ(qa2, 2) DOQ(qa3, 3)
#undef DOQ

    a = wred_sum(a);
    if (lane == 0) {
      __hip_atomic_store(&states[(size_t)(t + 1) * NS + col], a * (1.0f / 4096.0f),
                         __ATOMIC_RELAXED, __HIP_MEMORY_SCOPE_AGENT);
    }
    __syncthreads();  // all 16 waves' stores drained (vmcnt) before signal
    if (tid == 0) {
      __hip_atomic_store(&flags[blk], (unsigned)(t + 1),
                         __ATOMIC_RELEASE, __HIP_MEMORY_SCOPE_AGENT);
    }
    qa0 = qb0; qa1 = qb1; qa2 = qb2; qa3 = qb3;
  }
}

// ---- K4: out[t,:] = (s_t @ On[:,y,:]) / sum(s_t) ----
__global__ void output_kernel(const float* __restrict__ states, const float* __restrict__ On,
                              const int* __restrict__ seq, float* __restrict__ out) {
  const int t = blockIdx.x;
  const int y = seq[t];
  const float* s = states + (size_t)t * NS;
  const int tid = threadIdx.x;
  float a0 = 0, a1 = 0, a2 = 0, a3 = 0, mass = 0;
  for (int q = 0; q < 16; ++q) {
    const int i = q * 256 + tid;
    const float sv = s[i];
    const float4 on = *(const float4*)(On + ((size_t)i * 2 + y) * 4);
    a0 += sv * on.x; a1 += sv * on.y; a2 += sv * on.z; a3 += sv * on.w; mass += sv;
  }
  a0 = wred_sum(a0); a1 = wred_sum(a1); a2 = wred_sum(a2); a3 = wred_sum(a3);
  mass = wred_sum(mass);
  __shared__ float red[4][5];
  const int lane = tid & 63, wave = tid >> 6;
  if (lane == 0) { red[wave][0] = a0; red[wave][1] = a1; red[wave][2] = a2;
                   red[wave][3] = a3; red[wave][4] = mass; }
  __syncthreads();
  if (tid == 0) {
    float b0 = red[0][0] + red[1][0] + red[2][0] + red[3][0];
    float b1 = red[0][1] + red[1][1] + red[2][1] + red[3][1];
    float b2 = red[0][2] + red[1][2] + red[2][2] + red[3][2];
    float b3 = red[0][3] + red[1][3] + red[2][3] + red[3][3];
    float M  = red[0][4] + red[1][4] + red[2][4] + red[3][4];
    const float inv = 1.0f / M;
    *(float4*)(out + (size_t)t * 4) = make_float4(b0 * inv, b1 * inv, b2 * inv, b3 * inv);
  }
}

extern "C" void kernel_launch(void* const* d_in, const int* in_sizes, int n_in,
                              void* d_out, int out_size, void* d_ws, size_t ws_size,
                              hipStream_t stream) {
  const int* seq    = (const int*)d_in[0];
  const float* T    = (const float*)d_in[1];
  const float* O    = (const float*)d_in[2];
  const float* init = (const float*)d_in[3];
  float* out = (float*)d_out;

  char* ws = (char*)d_ws;
  unsigned char* Tt8 = (unsigned char*)ws;                    // 32 MiB
  ushort_t* Tt16 = (ushort_t*)(ws + 33554432);                // 64 MiB (temp)
  float* states  = (float*)(ws + 33554432);                   // 32 MiB (reuse)
  float* On      = (float*)(ws + 33554432 + 67108864);
  float2* rstat  = (float2*)(ws + 33554432 + 67108864 + 131072);
  unsigned* flags = (unsigned*)(ws + 33554432 + 67108864 + 131072 + 65536);

  (void)hipMemsetAsync(flags, 0, NBLK * 4, stream);
  hipLaunchKernelGGL(rowstats_kernel, dim3(NS * 2), dim3(256), 0, stream, T, rstat);
  hipLaunchKernelGGL(transq_kernel, dim3(16, 256, 2), dim3(256), 0, stream, T, rstat, Tt16);
  hipLaunchKernelGGL(permq_kernel, dim3(NS * 2), dim3(256), 0, stream, Tt16, Tt8);
  hipLaunchKernelGGL(onnorm_kernel, dim3(32), dim3(256), 0, stream, O, On);
  hipLaunchKernelGGL(initstate_kernel, dim3(1), dim3(1024), 0, stream, init, states);

  void* kargs[] = { (void*)&Tt8, (void*)&seq, (void*)&states, (void*)&flags };
  (void)hipLaunchCooperativeKernel((void*)scan_kernel, dim3(NBLK), dim3(THR),
                                   kargs, 0, stream);

  hipLaunchKernelGGL(output_kernel, dim3(SEQ), dim3(256), 0, stream, states, On, seq, out);
}

// Round 7
// 5196.779 us; speedup vs baseline: 6.6944x; 2.6846x over previous
//
#include <hip/hip_runtime.h>
#include <hip/hip_bf16.h>

#define NS 4096
#define SEQ 2048
#define NBLK 256
#define THR 1024
#define NT 1023  // pair transitions: s_{2u} -> s_{2u+2}, u = 0..1022

typedef unsigned short ushort_t;
typedef float vfloat2 __attribute__((ext_vector_type(2)));
typedef float f32x4 __attribute__((ext_vector_type(4)));

__device__ __forceinline__ float wred_sum(float v) {
#pragma unroll
  for (int o = 32; o > 0; o >>= 1) v += __shfl_xor(v, o, 64);
  return v;
}
__device__ __forceinline__ float wred_max(float v) {
#pragma unroll
  for (int o = 32; o > 0; o >>= 1) v = fmaxf(v, __shfl_xor(v, o, 64));
  return v;
}

// ---- fp8 e4m3fn helpers (positive values only, ~[0.1, 440]) ----
#if __has_builtin(__builtin_amdgcn_cvt_pk_f32_fp8)
template <bool W>
__device__ __forceinline__ vfloat2 cvtpk(unsigned d) {
  return __builtin_amdgcn_cvt_pk_f32_fp8((int)d, W);
}
#else
template <bool W>
__device__ __forceinline__ vfloat2 cvtpk(unsigned d) {
  unsigned b0 = (d >> (W ? 16 : 0)) & 0x7fu;
  unsigned b1 = (d >> (W ? 24 : 8)) & 0x7fu;
  vfloat2 r;
  r.x = __uint_as_float((b0 << 20) + 0x3C000000u);
  r.y = __uint_as_float((b1 << 20) + 0x3C000000u);
  return r;
}
#endif

__device__ __forceinline__ unsigned char encf(float w) {
  // f32 -> e4m3fn, round-half-up; clamp keeps us in normal range, below NaN
  float v = fminf(fmaxf(w, 0.0157f), 440.0f);
  unsigned u = __float_as_uint(v);
  return (unsigned char)(((u + 0xC4080000u) >> 20) & 0x7Fu);
}

__device__ __forceinline__ float dot4_fp8(unsigned d, float4 s, float acc) {
  vfloat2 lo = cvtpk<false>(d);
  vfloat2 hi = cvtpk<true>(d);
  acc += s.x * lo.x; acc += s.y * lo.y;
  acc += s.z * hi.x; acc += s.w * hi.y;
  return acc;
}

// ---- K1a: per-row softmax stats of T; rstat.y = 4096/sum ----
__global__ void rowstats_kernel(const float* __restrict__ T, float2* __restrict__ rstat) {
  const int r = blockIdx.x;
  const float* row = T + (size_t)r * NS;
  const int tid = threadIdx.x;
  float4 v[4];
  float mx = -1e30f;
#pragma unroll
  for (int q = 0; q < 4; ++q) {
    v[q] = *(const float4*)(row + q * 1024 + tid * 4);
    mx = fmaxf(mx, fmaxf(fmaxf(v[q].x, v[q].y), fmaxf(v[q].z, v[q].w)));
  }
  __shared__ float redm[4], reds[4];
  mx = wred_max(mx);
  if ((tid & 63) == 0) redm[tid >> 6] = mx;
  __syncthreads();
  mx = fmaxf(fmaxf(redm[0], redm[1]), fmaxf(redm[2], redm[3]));
  float se = 0.f;
#pragma unroll
  for (int q = 0; q < 4; ++q)
    se += __expf(v[q].x - mx) + __expf(v[q].y - mx) + __expf(v[q].z - mx) + __expf(v[q].w - mx);
  se = wred_sum(se);
  if ((tid & 63) == 0) reds[tid >> 6] = se;
  __syncthreads();
  if (tid == 0) {
    float tot = reds[0] + reds[1] + reds[2] + reds[3];
    rstat[r] = make_float2(mx, 4096.0f / tot);
  }
}

// ---- build R_s fp8: R[j][k] = enc(Tn[k,s,j]*4096), row-major j x k ----
__global__ void buildR_kernel(const float* __restrict__ T, const float2* __restrict__ rstat,
                              unsigned char* __restrict__ R, int s) {
  const int j = blockIdx.x * 256 + threadIdx.x;  // grid.x = 16
  const int i0 = blockIdx.y * 16;                // grid.y = 256
  unsigned char ob[16] __attribute__((aligned(16)));
#pragma unroll
  for (int ii = 0; ii < 16; ++ii) {
    const int r = (i0 + ii) * 2 + s;
    const float2 st = rstat[r];
    const float w = __expf(T[(size_t)r * NS + j] - st.x) * st.y;
    ob[ii] = encf(w);
  }
  *(uint4*)(R + (size_t)j * NS + i0) = *(uint4*)ob;
}

// ---- build M_s fp8: M[i][k] = enc(Tn[i,s,k]*4096), row-major i x k ----
__global__ void buildM_kernel(const float* __restrict__ T, const float2* __restrict__ rstat,
                              unsigned char* __restrict__ M, int s) {
  const int i = blockIdx.x;  // 4096
  const int r = i * 2 + s;
  const float2 st = rstat[r];
  const int k0 = threadIdx.x * 16;  // 256 thr
  unsigned char ob[16] __attribute__((aligned(16)));
#pragma unroll
  for (int kk = 0; kk < 16; ++kk) {
    const float w = __expf(T[(size_t)r * NS + k0 + kk] - st.x) * st.y;
    ob[kk] = encf(w);
  }
  *(uint4*)(M + (size_t)i * NS + k0) = *(uint4*)ob;
}

// ---- pair GEMM: C[j][i] = enc( (1/4096) * sum_k A[j][k]*B[i][k] ) ----
// A = R_b (row-major), B = M_a (row-major, acts as B^T). C = 4096*P_ab^T.
__global__ void __launch_bounds__(256)
pairgemm_kernel(const unsigned char* __restrict__ A, const unsigned char* __restrict__ B,
                unsigned char* __restrict__ C) {
  const int tid = threadIdx.x;
  const int lane = tid & 63;
  const int wv = tid >> 6;  // 4 waves, 2x2
  const int j0 = blockIdx.y * 128 + (wv >> 1) * 64;
  const int i0 = blockIdx.x * 128 + (wv & 1) * 64;
  const int lrow = lane & 15;
  const int lkg = (lane >> 4) * 8;

  f32x4 acc[4][4] = {};
  const unsigned char* Ab = A + (size_t)(j0 + lrow) * NS + lkg;
  const unsigned char* Bb = B + (size_t)(i0 + lrow) * NS + lkg;
  for (int kc = 0; kc < NS; kc += 32) {
    long long av[4], bv[4];
#pragma unroll
    for (int m = 0; m < 4; ++m) {
      av[m] = *(const long long*)(Ab + (size_t)(m * 16) * NS + kc);
      bv[m] = *(const long long*)(Bb + (size_t)(m * 16) * NS + kc);
    }
#pragma unroll
    for (int m = 0; m < 4; ++m)
#pragma unroll
      for (int n = 0; n < 4; ++n)
        acc[m][n] = __builtin_amdgcn_mfma_f32_16x16x32_fp8_fp8(av[m], bv[n], acc[m][n], 0, 0, 0);
  }
  const int orow = (lane >> 4) * 4;
#pragma unroll
  for (int m = 0; m < 4; ++m)
#pragma unroll
    for (int n = 0; n < 4; ++n)
#pragma unroll
      for (int r = 0; r < 4; ++r) {
        const int j = j0 + m * 16 + orow + r;
        const int i = i0 + n * 16 + lrow;
        C[(size_t)j * NS + i] = encf(acc[m][n][r] * (1.0f / 4096.0f));
      }
}

// ---- in-place per-row byte permute into the scan's LDS-friendly layout.
// dst o = q*1024 + l*16 + r*4 + e  <-  src i = q*1024 + r*256 + l*4 + e
__global__ void permq8_kernel(unsigned char* __restrict__ Q) {
  unsigned char* row = Q + ((size_t)blockIdx.y * NS + blockIdx.x) * NS;
  const int t = threadIdx.x;  // 256 = 4 waves; wave w handles q = w section
  const int q = t >> 6, l = t & 63;
  uint4 o;
  o.x = *(const unsigned*)(row + q * 1024 + 0 * 256 + l * 4);
  o.y = *(const unsigned*)(row + q * 1024 + 1 * 256 + l * 4);
  o.z = *(const unsigned*)(row + q * 1024 + 2 * 256 + l * 4);
  o.w = *(const unsigned*)(row + q * 1024 + 3 * 256 + l * 4);
  *(uint4*)(row + q * 1024 + l * 16) = o;  // wave-lockstep: loads precede store
}

// ---- normalize O (f32) ----
__global__ void onnorm_kernel(const float* __restrict__ O, float* __restrict__ On) {
  const int r = blockIdx.x * blockDim.x + threadIdx.x;
  if (r >= NS * 2) return;
  float4 v = *(const float4*)(O + (size_t)r * 4);
  float mx = fmaxf(fmaxf(v.x, v.y), fmaxf(v.z, v.w));
  float e0 = __expf(v.x - mx), e1 = __expf(v.y - mx), e2 = __expf(v.z - mx), e3 = __expf(v.w - mx);
  float inv = 1.0f / (e0 + e1 + e2 + e3);
  *(float4*)(On + (size_t)r * 4) = make_float4(e0 * inv, e1 * inv, e2 * inv, e3 * inv);
}

// ---- E_{a,b}[i][c] = sum_k Tn[i,a,k] * On[k,b,c]  (exact f32) ----
__global__ void emat_kernel(const float* __restrict__ T, const float2* __restrict__ rstat,
                            const float* __restrict__ On, float* __restrict__ E) {
  const int i = blockIdx.x, a = blockIdx.y;
  const int r = i * 2 + a;
  const float2 st = rstat[r];
  const int tid = threadIdx.x;  // 256
  float e0[4] = {}, e1[4] = {};
  for (int q = 0; q < 16; ++q) {
    const int k = q * 256 + tid;
    const float w = __expf(T[(size_t)r * NS + k] - st.x) * st.y * (1.0f / 4096.0f);
    const float4 o0 = *(const float4*)(On + (size_t)(k * 2 + 0) * 4);
    const float4 o1 = *(const float4*)(On + (size_t)(k * 2 + 1) * 4);
    e0[0] += w * o0.x; e0[1] += w * o0.y; e0[2] += w * o0.z; e0[3] += w * o0.w;
    e1[0] += w * o1.x; e1[1] += w * o1.y; e1[2] += w * o1.z; e1[3] += w * o1.w;
  }
  __shared__ float red[4][8];
  const int lane = tid & 63, wave = tid >> 6;
#pragma unroll
  for (int c = 0; c < 4; ++c) { e0[c] = wred_sum(e0[c]); e1[c] = wred_sum(e1[c]); }
  if (lane == 0) {
#pragma unroll
    for (int c = 0; c < 4; ++c) { red[wave][c] = e0[c]; red[wave][4 + c] = e1[c]; }
  }
  __syncthreads();
  if (tid == 0) {
    float f0[4], f1[4];
#pragma unroll
    for (int c = 0; c < 4; ++c) {
      f0[c] = red[0][c] + red[1][c] + red[2][c] + red[3][c];
      f1[c] = red[0][4 + c] + red[1][4 + c] + red[2][4 + c] + red[3][4 + c];
    }
    *(float4*)(E + ((size_t)(a * 2 + 0) * NS + i) * 4) = make_float4(f0[0], f0[1], f0[2], f0[3]);
    *(float4*)(E + ((size_t)(a * 2 + 1) * NS + i) * 4) = make_float4(f1[0], f1[1], f1[2], f1[3]);
  }
}

// ---- s0 = softmax(init) * 4096 ----
__global__ void initstate_kernel(const float* __restrict__ init, float* __restrict__ s0) {
  const int tid = threadIdx.x;  // 1024
  float4 v = *(const float4*)(init + tid * 4);
  float mx = fmaxf(fmaxf(v.x, v.y), fmaxf(v.z, v.w));
  __shared__ float red[16];
  mx = wred_max(mx);
  if ((tid & 63) == 0) red[tid >> 6] = mx;
  __syncthreads();
  float MX = -1e30f;
#pragma unroll
  for (int k = 0; k < 16; ++k) MX = fmaxf(MX, red[k]);
  __syncthreads();
  float e0 = __expf(v.x - MX), e1 = __expf(v.y - MX), e2 = __expf(v.z - MX), e3 = __expf(v.w - MX);
  float se = wred_sum(e0 + e1 + e2 + e3);
  if ((tid & 63) == 0) red[tid >> 6] = se;
  __syncthreads();
  float tot = 0.f;
#pragma unroll
  for (int k = 0; k < 16; ++k) tot += red[k];
  float inv = 4096.0f / tot;
  *(float4*)(s0 + tid * 4) = make_float4(e0 * inv, e1 * inv, e2 * inv, e3 * inv);
}

// ---- K3: pair-fused scan, 1023 rounds. Flag store is RELAXED: state stores
// are agent write-through atomics, __syncthreads drains vmcnt(0), so order
// is already guaranteed — no release (no buffer_wbl2) on the critical path.
__global__ void __launch_bounds__(THR, 4)
scan_kernel(const unsigned char* __restrict__ Pt8, const int* __restrict__ seq,
            float* __restrict__ states, unsigned* __restrict__ flags) {
  __shared__ float smem[NS];
  __shared__ int spid[1024];
  const int tid = threadIdx.x;
  const int lane = tid & 63;
  const int wave = tid >> 6;
  const int blk = blockIdx.x;
  const int col = blk * 16 + wave;

  if (tid < 1024) spid[tid] = seq[2 * tid] * 2 + seq[2 * tid + 1];
  __syncthreads();

  const unsigned* fp = flags + lane * 4;  // each lane watches 4 blocks

  uint4 qa0, qa1, qa2, qa3, qb0, qb1, qb2, qb3;
  {
    const unsigned char* cb = Pt8 + ((size_t)spid[0] * NS + col) * NS + lane * 16;
    qa0 = *(const uint4*)(cb);
    qa1 = *(const uint4*)(cb + 1024);
    qa2 = *(const uint4*)(cb + 2048);
    qa3 = *(const uint4*)(cb + 3072);
  }

  for (int u = 0; u < NT; ++u) {
    // (a) prefetch next pair-matrix columns (overlaps the wait)
    if (u + 1 < NT) {
      const unsigned char* cb = Pt8 + ((size_t)spid[u + 1] * NS + col) * NS + lane * 16;
      qb0 = *(const uint4*)(cb);
      qb1 = *(const uint4*)(cb + 1024);
      qb2 = *(const uint4*)(cb + 2048);
      qb3 = *(const uint4*)(cb + 3072);
    }

    // (b) wait for epoch u
    if (u > 0) {
      if (wave == 0) {
        const unsigned tgt = (unsigned)u;
        unsigned f0, f1, f2, f3;
        do {
          f0 = __hip_atomic_load(fp + 0, __ATOMIC_RELAXED, __HIP_MEMORY_SCOPE_AGENT);
          f1 = __hip_atomic_load(fp + 1, __ATOMIC_RELAXED, __HIP_MEMORY_SCOPE_AGENT);
          f2 = __hip_atomic_load(fp + 2, __ATOMIC_RELAXED, __HIP_MEMORY_SCOPE_AGENT);
          f3 = __hip_atomic_load(fp + 3, __ATOMIC_RELAXED, __HIP_MEMORY_SCOPE_AGENT);
        } while (!__all(f0 >= tgt && f1 >= tgt && f2 >= tgt && f3 >= tgt));
      }
      __syncthreads();
    }

    // (c) stage state u -> LDS
    const float* s = states + (size_t)u * NS;
    *(float4*)(smem + tid * 4) = *(const float4*)(s + tid * 4);
    __syncthreads();

    // (d) compute
    float a = 0.f;
#define DOQ(Q, qi)                                                     \
    {                                                                  \
      float4 s0 = *(const float4*)(smem + qi * 1024 + lane * 4);       \
      float4 s1 = *(const float4*)(smem + qi * 1024 + 256 + lane * 4); \
      float4 s2 = *(const float4*)(smem + qi * 1024 + 512 + lane * 4); \
      float4 s3 = *(const float4*)(smem + qi * 1024 + 768 + lane * 4); \
      a = dot4_fp8(Q.x, s0, a);                                        \
      a = dot4_fp8(Q.y, s1, a);                                        \
      a = dot4_fp8(Q.z, s2, a);                                        \
      a = dot4_fp8(Q.w, s3, a);                                        \
    }
    DOQ(qa0, 0) DOQ(qa1, 1) DOQ(qa2, 2) DOQ(qa3, 3)
#undef DOQ

    a = wred_sum(a);
    if (lane == 0) {
      __hip_atomic_store(&states[(size_t)(u + 1) * NS + col], a * (1.0f / 4096.0f),
                         __ATOMIC_RELAXED, __HIP_MEMORY_SCOPE_AGENT);
    }
    __syncthreads();  // vmcnt(0): all 16 waves' WT stores acked before signal
    if (tid == 0) {
      __hip_atomic_store(&flags[blk], (unsigned)(u + 1),
                         __ATOMIC_RELAXED, __HIP_MEMORY_SCOPE_AGENT);
    }
    qa0 = qb0; qa1 = qb1; qa2 = qb2; qa3 = qb3;
  }
}

// ---- K4: even t: out = (s_u @ On[:,y])/mass; odd t: out = (s_u @ E_ab)/mass
__global__ void output_kernel(const float* __restrict__ states, const float* __restrict__ On,
                              const float* __restrict__ E, const int* __restrict__ seq,
                              float* __restrict__ out) {
  const int t = blockIdx.x;
  const int y = seq[t];
  const int u = t >> 1;
  const bool odd = t & 1;
  const float* s = states + (size_t)u * NS;
  const float4* W = odd ? (const float4*)(E + ((size_t)(seq[t - 1] * 2 + y) * NS) * 4) : nullptr;
  const float4* Onf = (const float4*)On;
  const int tid = threadIdx.x;
  float a0 = 0, a1 = 0, a2 = 0, a3 = 0, mass = 0;
  for (int q = 0; q < 16; ++q) {
    const int i = q * 256 + tid;
    const float sv = s[i];
    const float4 w = odd ? W[i] : Onf[i * 2 + y];
    a0 += sv * w.x; a1 += sv * w.y; a2 += sv * w.z; a3 += sv * w.w; mass += sv;
  }
  a0 = wred_sum(a0); a1 = wred_sum(a1); a2 = wred_sum(a2); a3 = wred_sum(a3);
  mass = wred_sum(mass);
  __shared__ float red[4][5];
  const int lane = tid & 63, wave = tid >> 6;
  if (lane == 0) { red[wave][0] = a0; red[wave][1] = a1; red[wave][2] = a2;
                   red[wave][3] = a3; red[wave][4] = mass; }
  __syncthreads();
  if (tid == 0) {
    float b0 = red[0][0] + red[1][0] + red[2][0] + red[3][0];
    float b1 = red[0][1] + red[1][1] + red[2][1] + red[3][1];
    float b2 = red[0][2] + red[1][2] + red[2][2] + red[3][2];
    float b3 = red[0][3] + red[1][3] + red[2][3] + red[3][3];
    float M  = red[0][4] + red[1][4] + red[2][4] + red[3][4];
    const float inv = 1.0f / M;
    *(float4*)(out + (size_t)t * 4) = make_float4(b0 * inv, b1 * inv, b2 * inv, b3 * inv);
  }
}

extern "C" void kernel_launch(void* const* d_in, const int* in_sizes, int n_in,
                              void* d_out, int out_size, void* d_ws, size_t ws_size,
                              hipStream_t stream) {
  const int* seq    = (const int*)d_in[0];
  const float* T    = (const float*)d_in[1];
  const float* O    = (const float*)d_in[2];
  const float* init = (const float*)d_in[3];
  float* out = (float*)d_out;

  char* ws = (char*)d_ws;
  // layout (peak ~96.5 MiB):
  //  [0,16M):   Rcur fp8 (GEMM A); later overlaid by states f32 [1024][4096]
  //  [16M,32M): Mcur fp8 (GEMM B)
  //  [32M,96M): Q8/Pt8 fp8 [4][4096][4096]
  //  [96M,..):  On | rstat | E | flags
  unsigned char* Rcur = (unsigned char*)ws;
  unsigned char* Mcur = (unsigned char*)(ws + 16777216);
  unsigned char* Q8   = (unsigned char*)(ws + 33554432);
  float* states = (float*)ws;  // after GEMMs
  char* sm = ws + 100663296;
  float* On      = (float*)(sm);
  float2* rstat  = (float2*)(sm + 131072);
  float* E       = (float*)(sm + 131072 + 65536);
  unsigned* flags = (unsigned*)(sm + 131072 + 65536 + 262144);

  (void)hipMemsetAsync(flags, 0, NBLK * 4, stream);
  hipLaunchKernelGGL(rowstats_kernel, dim3(NS * 2), dim3(256), 0, stream, T, rstat);
  hipLaunchKernelGGL(onnorm_kernel, dim3(32), dim3(256), 0, stream, O, On);

  // pair GEMMs, grouped by b (A=R_b rebuilt 2x, B=M_a rebuilt 4x)
  hipLaunchKernelGGL(buildR_kernel, dim3(16, 256), dim3(256), 0, stream, T, rstat, Rcur, 0);
  hipLaunchKernelGGL(buildM_kernel, dim3(NS), dim3(256), 0, stream, T, rstat, Mcur, 0);
  hipLaunchKernelGGL(pairgemm_kernel, dim3(32, 32), dim3(256), 0, stream, Rcur, Mcur,
                     Q8 + (size_t)0 * 16777216);  // pid0: a=0,b=0
  hipLaunchKernelGGL(buildM_kernel, dim3(NS), dim3(256), 0, stream, T, rstat, Mcur, 1);
  hipLaunchKernelGGL(pairgemm_kernel, dim3(32, 32), dim3(256), 0, stream, Rcur, Mcur,
                     Q8 + (size_t)2 * 16777216);  // pid2: a=1,b=0
  hipLaunchKernelGGL(buildR_kernel, dim3(16, 256), dim3(256), 0, stream, T, rstat, Rcur, 1);
  hipLaunchKernelGGL(buildM_kernel, dim3(NS), dim3(256), 0, stream, T, rstat, Mcur, 0);
  hipLaunchKernelGGL(pairgemm_kernel, dim3(32, 32), dim3(256), 0, stream, Rcur, Mcur,
                     Q8 + (size_t)1 * 16777216);  // pid1: a=0,b=1
  hipLaunchKernelGGL(buildM_kernel, dim3(NS), dim3(256), 0, stream, T, rstat, Mcur, 1);
  hipLaunchKernelGGL(pairgemm_kernel, dim3(32, 32), dim3(256), 0, stream, Rcur, Mcur,
                     Q8 + (size_t)3 * 16777216);  // pid3: a=1,b=1

  hipLaunchKernelGGL(permq8_kernel, dim3(NS, 4), dim3(256), 0, stream, Q8);
  hipLaunchKernelGGL(emat_kernel, dim3(NS, 2), dim3(256), 0, stream, T, rstat, On, E);
  hipLaunchKernelGGL(initstate_kernel, dim3(1), dim3(1024), 0, stream, init, states);

  void* kargs[] = { (void*)&Q8, (void*)&seq, (void*)&states, (void*)&flags };
  (void)hipLaunchCooperativeKernel((void*)scan_kernel, dim3(NBLK), dim3(THR),
                                   kargs, 0, stream);

  hipLaunchKernelGGL(output_kernel, dim3(SEQ), dim3(256), 0, stream, states, On, E, seq, out);
}